// Round 9
// baseline (128.071 us; speedup 1.0000x reference)
//
#include <hip/hip_runtime.h>
#include <hip/hip_bf16.h>
#include <math.h>

#define EPSN 1e-12f
typedef unsigned short ushort_t;

typedef float f32x4 __attribute__((ext_vector_type(4)));
typedef short s16x8 __attribute__((ext_vector_type(8)));
typedef unsigned short u16x8 __attribute__((ext_vector_type(8)));
typedef unsigned short u16x4 __attribute__((ext_vector_type(4)));

__device__ __forceinline__ void gload_lds16(const void* g, void* l) {
  __builtin_amdgcn_global_load_lds((const __attribute__((address_space(1))) void*)g,
                                   (__attribute__((address_space(3))) void*)l, 16, 0, 0);
}

// ---------------- K0: per-token sum of squares -> 8 partials ----------------
__global__ void k0_ssq(const float* __restrict__ x, float* __restrict__ ssq8) {
  int b8 = blockIdx.x >> 3;
  int cc = blockIdx.x & 7;
  int t = threadIdx.x;
  int s4 = (t & 15) * 4;
  int cg = t >> 4;
  const float* xp = x + (size_t)b8 * 65536 + (size_t)cc * 128 * 64;
  float4 a = {0.f, 0.f, 0.f, 0.f};
#pragma unroll
  for (int j = 0; j < 8; ++j) {
    int c = cg + j * 16;
    float4 v = *(const float4*)(xp + (size_t)c * 64 + s4);
    a.x = fmaf(v.x, v.x, a.x);
    a.y = fmaf(v.y, v.y, a.y);
    a.z = fmaf(v.z, v.z, a.z);
    a.w = fmaf(v.w, v.w, a.w);
  }
  __shared__ float red[16][68];
  *(float4*)&red[cg][s4] = a;
  __syncthreads();
  if (t < 64) {
    float s = 0.f;
#pragma unroll
    for (int g = 0; g < 16; ++g) s += red[g][t];
    ssq8[cc * 4096 + b8 * 64 + t] = s;
  }
}

// ---------------- K1: transpose + scale -> xnb bf16 [tm][c] ----------------
__global__ void k1_transpose(const float* __restrict__ x, const float* __restrict__ ssq8,
                             __hip_bfloat16* __restrict__ xnb) {
  int ct = blockIdx.x;
  int b8 = blockIdx.y;
  int t = threadIdx.x;
  __shared__ float tile[64][65];
  __shared__ float ivs[64];
  if (t < 64) {
    float s = 0.f;
#pragma unroll
    for (int cc = 0; cc < 8; ++cc) s += ssq8[cc * 4096 + b8 * 64 + t];
    ivs[t] = rsqrtf(fmaxf(s, 1e-24f));
  }
  int s = t & 63, cq = t >> 6;
  const float* xp = x + (size_t)b8 * 65536 + (size_t)ct * 64 * 64;
#pragma unroll
  for (int r = 0; r < 16; ++r) {
    int cl = cq * 16 + r;
    tile[cl][s] = xp[cl * 64 + s];
  }
  __syncthreads();
  int cl = t & 63, sq = t >> 6;
#pragma unroll
  for (int r = 0; r < 16; ++r) {
    int smm = sq * 16 + r;
    int tm = b8 * 64 + smm;
    xnb[(size_t)tm * 1024 + ct * 64 + cl] = __float2bfloat16(tile[cl][smm] * ivs[smm]);
  }
}

// ---------------- kpack2: Wib + Wgkx (+gate rows, zero pad) + bWg + WibT (transposed) ------
__global__ void kpack2(const float* __restrict__ Wi, const float* __restrict__ Wgk,
                       const float* __restrict__ W_g, const float* __restrict__ b_inp,
                       const float* __restrict__ b_g, __hip_bfloat16* __restrict__ oWi,
                       __hip_bfloat16* __restrict__ oWx, ushort_t* __restrict__ oWibT,
                       float* __restrict__ bWg) {
  int bid = blockIdx.x;
  int t = threadIdx.x;
  if (bid < 2048) {
    int i = (bid * 256 + t) * 4;
    float4 v = *(const float4*)(Wi + i);
    oWi[i + 0] = __float2bfloat16(v.x);
    oWi[i + 1] = __float2bfloat16(v.y);
    oWi[i + 2] = __float2bfloat16(v.z);
    oWi[i + 3] = __float2bfloat16(v.w);
  } else if (bid < 4096) {
    int i = ((bid - 2048) * 256 + t) * 4;
    float4 v = *(const float4*)(Wgk + i);
    oWx[i + 0] = __float2bfloat16(v.x);
    oWx[i + 1] = __float2bfloat16(v.y);
    oWx[i + 2] = __float2bfloat16(v.z);
    oWx[i + 3] = __float2bfloat16(v.w);
  } else if (bid < 4112) {
    int i = (bid - 4096) * 1024 + t * 4;  // 16 blocks: 8 gate rows
    float4 v = *(const float4*)(W_g + i);
    __hip_bfloat16* o = oWx + 1024 * 2048 + i;
    o[0] = __float2bfloat16(v.x);
    o[1] = __float2bfloat16(v.y);
    o[2] = __float2bfloat16(v.z);
    o[3] = __float2bfloat16(v.w);
  } else if (bid < 4352) {
    int i = (bid - 4112) * 1024 + t * 4;  // 240 blocks: 120 zero rows
    ushort_t* o = (ushort_t*)(oWx + 1032 * 2048) + i;
    *(u16x4*)o = (u16x4){0, 0, 0, 0};
  } else if (bid < 4360) {
    int j = bid - 4352;  // 0..7
    const float* row = W_g + (size_t)j * 2048;
    float s = 0.f;
    for (int c = t; c < 2048; c += 256) s = fmaf(b_inp[c], row[c], s);
    __shared__ float red[256];
    red[t] = s;
    __syncthreads();
    for (int o = 128; o > 0; o >>= 1) {
      if (t < o) red[t] += red[t + o];
      __syncthreads();
    }
    if (t == 0) bWg[j] = red[0] + b_g[j];
  } else {
    // WibT[1024 c][2048 c'] = cast-transpose of W_inp[2048 c'][1024 c]; 512 tiles 64x64
    int tt = bid - 4360;
    int cp0 = (tt >> 4) * 64;  // c' base
    int c0 = (tt & 15) * 64;   // c base
    __shared__ ushort_t tile[64][72];
    int r = t >> 2, cs = (t & 3) * 16;
    const float* src = Wi + (size_t)(cp0 + r) * 1024 + c0 + cs;
#pragma unroll
    for (int j = 0; j < 16; j += 4) {
      float4 v = *(const float4*)(src + j);
      __hip_bfloat16 h0 = __float2bfloat16(v.x), h1 = __float2bfloat16(v.y);
      __hip_bfloat16 h2 = __float2bfloat16(v.z), h3 = __float2bfloat16(v.w);
      tile[r][cs + j + 0] = *(ushort_t*)&h0;
      tile[r][cs + j + 1] = *(ushort_t*)&h1;
      tile[r][cs + j + 2] = *(ushort_t*)&h2;
      tile[r][cs + j + 3] = *(ushort_t*)&h3;
    }
    __syncthreads();
    int c = t >> 2, ms = (t & 3) * 16;
    u16x8 o0, o1;
#pragma unroll
    for (int j = 0; j < 8; ++j) o0[j] = tile[ms + j][c];
#pragma unroll
    for (int j = 0; j < 8; ++j) o1[j] = tile[ms + 8 + j][c];
    ushort_t* dst = oWibT + (size_t)(c0 + c) * 2048 + cp0 + ms;
    *(u16x8*)dst = o0;
    *(u16x8*)(dst + 8) = o1;
  }
}

// ---------------- bf16 MFMA NT GEMM: 128x128, BK=64, 8 waves, dbuf, swizzle, counted vmcnt ----
// C[M,N] (bf16) = A[M,K] @ B[N,K]^T, all bf16.
__launch_bounds__(512, 4)
__global__ void gemm_nt_bf16(const ushort_t* __restrict__ A, const ushort_t* __restrict__ B,
                             ushort_t* __restrict__ C, int K, int N) {
  __shared__ alignas(16) ushort_t SH[32768];  // 64 KB: Ash[2] | Bsh[2]
  const int tid = threadIdx.x;
  const int m0 = blockIdx.y * 128, n0 = blockIdx.x * 128;
  const int w = tid >> 6, l = tid & 63;
  const int wr = w >> 2, wc = w & 3;  // 2x4 wave grid; per-wave 64m x 32n
  const int srow = w * 8 + (l >> 3);
  const int ksw = ((l & 7) ^ (l >> 3)) * 8;
  const ushort_t* Ag0 = A + (size_t)(m0 + srow) * K + ksw;
  const ushort_t* Ag1 = A + (size_t)(m0 + 64 + srow) * K + ksw;
  const ushort_t* Bg0 = B + (size_t)(n0 + srow) * K + ksw;
  const ushort_t* Bg1 = B + (size_t)(n0 + 64 + srow) * K + ksw;
  const int l0 = w * 512;
  const int l1 = 4096 + w * 512;

  f32x4 acc[4][2];
#pragma unroll
  for (int i = 0; i < 4; ++i)
#pragma unroll
    for (int j = 0; j < 2; ++j) acc[i][j] = (f32x4){0.f, 0.f, 0.f, 0.f};

  const int sw = l & 7, qq = l >> 4;

#define ASH(buf) (SH + (buf)*8192)
#define BSH(buf) (SH + 16384 + (buf)*8192)
#define STAGE(buf, k0)                               \
  {                                                  \
    gload_lds16(Ag0 + (k0), ASH(buf) + l0);          \
    gload_lds16(Ag1 + (k0), ASH(buf) + l1);          \
    gload_lds16(Bg0 + (k0), BSH(buf) + l0);          \
    gload_lds16(Bg1 + (k0), BSH(buf) + l1);          \
  }

#define COMPUTE(buf)                                                                     \
  {                                                                                      \
    s16x8 af[4][2], bf[2][2];                                                            \
    _Pragma("unroll") for (int kk = 0; kk < 2; ++kk) {                                   \
      int slot = (((kk << 2) + qq) ^ sw) * 8;                                            \
      _Pragma("unroll") for (int mi = 0; mi < 4; ++mi)                                   \
          af[mi][kk] = *(const s16x8*)&ASH(buf)[(wr * 64 + mi * 16 + (l & 15)) * 64 +    \
                                               slot];                                   \
      _Pragma("unroll") for (int ni = 0; ni < 2; ++ni)                                   \
          bf[ni][kk] = *(const s16x8*)&BSH(buf)[(wc * 32 + ni * 16 + (l & 15)) * 64 +    \
                                               slot];                                   \
    }                                                                                    \
    _Pragma("unroll") for (int kk = 0; kk < 2; ++kk)                                     \
        _Pragma("unroll") for (int mi = 0; mi < 4; ++mi)                                 \
            _Pragma("unroll") for (int ni = 0; ni < 2; ++ni)                             \
                acc[mi][ni] = __builtin_amdgcn_mfma_f32_16x16x32_bf16(af[mi][kk],        \
                                                                     bf[ni][kk],        \
                                                                     acc[mi][ni], 0, 0, 0); \
  }

  const int nt = K >> 6;
  STAGE(0, 0);
  int buf = 0;
  for (int t = 0; t < nt - 1; ++t) {
    STAGE(buf ^ 1, (t + 1) << 6);
    asm volatile("s_waitcnt vmcnt(4)" ::: "memory");
    __builtin_amdgcn_s_barrier();
    asm volatile("" ::: "memory");
    COMPUTE(buf);
    asm volatile("" ::: "memory");
    __builtin_amdgcn_s_barrier();
    buf ^= 1;
  }
  asm volatile("s_waitcnt vmcnt(0)" ::: "memory");
  __builtin_amdgcn_s_barrier();
  asm volatile("" ::: "memory");
  COMPUTE(buf);
#undef STAGE
#undef COMPUTE
#undef ASH
#undef BSH

#pragma unroll
  for (int mi = 0; mi < 4; ++mi) {
    int row = m0 + wr * 64 + mi * 16 + (l >> 4) * 4;
#pragma unroll
    for (int ni = 0; ni < 2; ++ni) {
      int col = n0 + wc * 32 + ni * 16 + (l & 15);
#pragma unroll
      for (int r = 0; r < 4; ++r) {
        __hip_bfloat16 hb = __float2bfloat16(acc[mi][ni][r]);
        C[(size_t)(row + r) * N + col] = *(ushort_t*)&hb;
      }
    }
  }
}

// ---------------- K5: row softmax over tokens + gate sigmoid, one wave per (q,b) ----------------
// logitsTb bf16 [1152 q][4096 tm]: rows 0-1023 cluster logits, rows 1024-1031 gate logits.
__launch_bounds__(256)
__global__ void k5_softmax(const ushort_t* __restrict__ logitsTb, const float* __restrict__ bWg,
                           float* __restrict__ colsumW, ushort_t* __restrict__ wbT) {
  int wv = (blockIdx.x << 2) + (threadIdx.x >> 6);
  int q = wv >> 3, b = wv & 7;
  int l = threadIdx.x & 63;
  int g = q >> 7;
  size_t base = (size_t)q * 4096 + b * 512 + l * 8;
  u16x8 v8 = *(const u16x8*)(logitsTb + base);
  float vs[8];
#pragma unroll
  for (int i = 0; i < 8; ++i) vs[i] = __uint_as_float(((unsigned)v8[i]) << 16);
  float M = vs[0];
#pragma unroll
  for (int i = 1; i < 8; ++i) M = fmaxf(M, vs[i]);
#pragma unroll
  for (int m = 1; m < 64; m <<= 1) M = fmaxf(M, __shfl_xor(M, m, 64));
  float e[8], S = 0.f;
#pragma unroll
  for (int i = 0; i < 8; ++i) {
    e[i] = expf(vs[i] - M);
    S += e[i];
  }
#pragma unroll
  for (int m = 1; m < 64; m <<= 1) S += __shfl_xor(S, m, 64);
  float R = 1.0f / S;
  u16x8 g8 = *(const u16x8*)(logitsTb + (size_t)(1024 + g) * 4096 + b * 512 + l * 8);
  float bg = bWg[g];
  float wv8[8], wsum = 0.f;
#pragma unroll
  for (int i = 0; i < 8; ++i) {
    float gl = __uint_as_float(((unsigned)g8[i]) << 16);
    float ag = 1.0f / (1.0f + expf(-(gl + bg)));
    wv8[i] = e[i] * R * ag;
    wsum += wv8[i];
  }
#pragma unroll
  for (int m = 1; m < 64; m <<= 1) wsum += __shfl_xor(wsum, m, 64);
  if (l == 0) colsumW[b * 1024 + q] = wsum;
  u16x8 o;
#pragma unroll
  for (int i = 0; i < 8; ++i) {
    __hip_bfloat16 hb = __float2bfloat16(wv8[i]);
    o[i] = *(ushort_t*)&hb;
  }
  *(u16x8*)(wbT + base) = o;
}

// ---------------- K6: VLAD einsum via MFMA, 64x64 tile, m-split 8, counted vmcnt ----------------
__launch_bounds__(256)
__global__ void k6_vlad_mfma(const ushort_t* __restrict__ wbT, const ushort_t* __restrict__ YcT,
                             float* __restrict__ vpart) {
  int kt = blockIdx.x >> 2, dt = blockIdx.x & 3;
  int ms = blockIdx.y, b = blockIdx.z;  // ms 0..7 (64 m each)
  __shared__ alignas(16) ushort_t Ash[2][4096];
  __shared__ alignas(16) ushort_t Bsh[2][4096];
  const int tid = threadIdx.x;
  const int w = tid >> 6, l = tid & 63;
  const int wr = w >> 1, wc = w & 1;
  const int crow = l >> 3;
  const int ksw = ((l & 7) ^ crow) * 8;

  const ushort_t* Ap[2];
  const ushort_t* Bp[2];
  int loff[2];
#pragma unroll
  for (int c = 0; c < 2; ++c) {
    int chunk = w * 2 + c;  // 0..7
    Ap[c] = wbT + (size_t)(kt * 64 + chunk * 8 + crow) * 4096 + b * 512 + ms * 64 + ksw;
    Bp[c] = YcT + (size_t)(dt * 64 + chunk * 8 + crow) * 4096 + b * 512 + ms * 64 + ksw;
    loff[c] = chunk * 512;
  }

  f32x4 acc[2][2];
#pragma unroll
  for (int i = 0; i < 2; ++i)
#pragma unroll
    for (int j = 0; j < 2; ++j) acc[i][j] = (f32x4){0.f, 0.f, 0.f, 0.f};

  const int sw = l & 7, qq = l >> 4;

#define STAGE6(buf, g)                                                       \
  {                                                                          \
    size_t offA = (size_t)(g)*524288;                                        \
    size_t offB = (size_t)(g)*1048576;                                       \
    gload_lds16(Ap[0] + offA, &Ash[buf][loff[0]]);                           \
    gload_lds16(Ap[1] + offA, &Ash[buf][loff[1]]);                           \
    gload_lds16(Bp[0] + offB, &Bsh[buf][loff[0]]);                           \
    gload_lds16(Bp[1] + offB, &Bsh[buf][loff[1]]);                           \
  }

#define COMPUTE6(buf)                                                                    \
  {                                                                                      \
    s16x8 af[2][2], bf[2][2];                                                            \
    _Pragma("unroll") for (int kk = 0; kk < 2; ++kk) {                                   \
      int slot = (((kk << 2) + qq) ^ sw) * 8;                                            \
      _Pragma("unroll") for (int mi = 0; mi < 2; ++mi) {                                 \
        af[mi][kk] = *(const s16x8*)&Ash[buf][(wr * 32 + mi * 16 + (l & 15)) * 64 +      \
                                             slot];                                     \
        bf[mi][kk] = *(const s16x8*)&Bsh[buf][(wc * 32 + mi * 16 + (l & 15)) * 64 +      \
                                             slot];                                     \
      }                                                                                  \
    }                                                                                    \
    _Pragma("unroll") for (int kk = 0; kk < 2; ++kk)                                     \
        _Pragma("unroll") for (int mi = 0; mi < 2; ++mi)                                 \
            _Pragma("unroll") for (int ni = 0; ni < 2; ++ni)                             \
                acc[mi][ni] = __builtin_amdgcn_mfma_f32_16x16x32_bf16(af[mi][kk],        \
                                                                     bf[ni][kk],        \
                                                                     acc[mi][ni], 0, 0, 0); \
  }

  STAGE6(0, 0);
  int buf = 0;
  for (int s = 0; s < 7; ++s) {  // 8 steps: one per g
    STAGE6(buf ^ 1, s + 1);
    asm volatile("s_waitcnt vmcnt(4)" ::: "memory");
    __builtin_amdgcn_s_barrier();
    asm volatile("" ::: "memory");
    COMPUTE6(buf);
    asm volatile("" ::: "memory");
    __builtin_amdgcn_s_barrier();
    buf ^= 1;
  }
  asm volatile("s_waitcnt vmcnt(0)" ::: "memory");
  __builtin_amdgcn_s_barrier();
  asm volatile("" ::: "memory");
  COMPUTE6(buf);
#undef STAGE6
#undef COMPUTE6

#pragma unroll
  for (int mi = 0; mi < 2; ++mi) {
    int row = kt * 64 + wr * 32 + mi * 16 + (l >> 4) * 4;
#pragma unroll
    for (int ni = 0; ni < 2; ++ni) {
      int col = dt * 64 + wc * 32 + ni * 16 + (l & 15);
#pragma unroll
      for (int r = 0; r < 4; ++r)
        vpart[((size_t)(ms * 8 + b) * 128 + row + r) * 256 + col] = acc[mi][ni][r];
    }
  }
}

// ---------------- K7: combine 8 partials + bias-part - S*centroid, intra-normalize ----------------
__global__ void k7_intranorm(const float* __restrict__ vpart, const float* __restrict__ colsumW,
                             const float* __restrict__ b_inp, const float* __restrict__ cent,
                             float* __restrict__ out, float* __restrict__ ss1) {
  int k = blockIdx.x;
  int b = blockIdx.y;
  int d = threadIdx.x;
  float S = 0.f, bp = 0.f;
#pragma unroll
  for (int g = 0; g < 8; ++g) {
    float cw = colsumW[b * 1024 + g * 128 + k];
    S += cw;
    bp = fmaf(b_inp[g * 256 + d], cw, bp);
  }
  size_t off = ((size_t)b * 128 + k) * 256 + d;
  float v = bp - S * cent[(size_t)k * 256 + d];
#pragma unroll
  for (int i = 0; i < 8; ++i) v += vpart[off + (size_t)i * 262144];
  float ss = v * v;
#pragma unroll
  for (int m = 1; m < 64; m <<= 1) ss += __shfl_xor(ss, m, 64);
  __shared__ float red[4];
  int lane = d & 63, wv = d >> 6;
  if (lane == 0) red[wv] = ss;
  __syncthreads();
  float tot = red[0] + red[1] + red[2] + red[3];
  float rinv = 1.0f / fmaxf(sqrtf(tot), EPSN);
  out[off] = v * rinv;
  if (d == 0) ss1[b * 128 + k] = tot * rinv * rinv;
}

// ---------------- K8: final global L2 norm ----------------
__global__ void k8_finalnorm(const float* __restrict__ ss1, float* __restrict__ out) {
  int b = blockIdx.x;
  int t = threadIdx.x;
  __shared__ float red[256];
  red[t] = (t < 128) ? ss1[b * 128 + t] : 0.f;
  __syncthreads();
  for (int o = 128; o > 0; o >>= 1) {
    if (t < o) red[t] += red[t + o];
    __syncthreads();
  }
  float rinv = 1.0f / fmaxf(sqrtf(red[0]), EPSN);
  float* op = out + (size_t)b * 32768;
  for (int i = t; i < 32768; i += 256) op[i] *= rinv;
}

extern "C" void kernel_launch(void* const* d_in, const int* in_sizes, int n_in,
                              void* d_out, int out_size, void* d_ws, size_t ws_size,
                              hipStream_t stream) {
  const float* x     = (const float*)d_in[0];
  const float* W_inp = (const float*)d_in[1];
  const float* b_inp = (const float*)d_in[2];
  const float* W_g   = (const float*)d_in[3];
  const float* b_g   = (const float*)d_in[4];
  const float* W_gk  = (const float*)d_in[5];
  // b_gk (d_in[6]) cancels in the token-axis softmax — unused.
  const float* cent  = (const float*)d_in[7];
  float* out = (float*)d_out;
  float* ws = (float*)d_ws;

  // workspace layout (float offsets), total 12,559,424 floats = 50.2 MB
  float* ssq8    = ws + 0;         // 32768
  float* colsumW = ws + 32768;     // 8192
  float* ss1     = ws + 40960;     // 1024
  float* bWg     = ws + 41984;     // 64
  __hip_bfloat16* xnb = (__hip_bfloat16*)(ws + 42048);    // [4096][1024] (2097152 fl)
  ushort_t* wbT  = (ushort_t*)xnb;                        // alias (xnb dead after GEMM2')
  __hip_bfloat16* Wib  = (__hip_bfloat16*)(ws + 2139200); // [2048][1024] (1048576 fl)
  ushort_t* WibT = (ushort_t*)(ws + 3187776);             // [1024][2048] (1048576 fl)
  float* vpart   = ws + 2139200;   // 2097152 fl, aliases Wib+WibT (dead before k6)
  __hip_bfloat16* Wgkx   = (__hip_bfloat16*)(ws + 4236352); // [1152][2048] (1179648 fl)
  __hip_bfloat16* Wcombx = (__hip_bfloat16*)(ws + 5416000); // [1152][1024] (589824 fl)
  ushort_t* YcT  = (ushort_t*)(ws + 6005824);             // [2048][4096] (4194304 fl)
  ushort_t* logitsTb = (ushort_t*)(ws + 10200128);        // [1152][4096] (2359296 fl)

  k0_ssq<<<512, 256, 0, stream>>>(x, ssq8);
  k1_transpose<<<dim3(16, 64), 256, 0, stream>>>(x, ssq8, xnb);
  kpack2<<<4872, 256, 0, stream>>>(W_inp, W_gk, W_g, b_inp, b_g, Wib, Wgkx, WibT, bWg);
  // GEMM0: Wcombx[1152,1024] = Wgkx[1152,2048] @ WibT[1024,2048]^T  (weights-only compose)
  gemm_nt_bf16<<<dim3(8, 9), 512, 0, stream>>>((const ushort_t*)Wgkx, WibT,
                                               (ushort_t*)Wcombx, 2048, 1024);
  // GEMM1': YcT[2048,4096] = Wib[2048,1024] @ xnb[4096,1024]^T  (direct transposed Yc)
  gemm_nt_bf16<<<dim3(32, 16), 512, 0, stream>>>((const ushort_t*)Wib, (const ushort_t*)xnb,
                                                 YcT, 1024, 4096);
  // GEMM2': logitsTb[1152,4096] = Wcombx[1152,1024] @ xnb[4096,1024]^T  (K halved via compose)
  gemm_nt_bf16<<<dim3(32, 9), 512, 0, stream>>>((const ushort_t*)Wcombx, (const ushort_t*)xnb,
                                                logitsTb, 1024, 4096);
  k5_softmax<<<2048, 256, 0, stream>>>(logitsTb, bWg, colsumW, wbT);
  k6_vlad_mfma<<<dim3(8, 8, 8), 256, 0, stream>>>(wbT, YcT, vpart);
  k7_intranorm<<<dim3(128, 8), 256, 0, stream>>>(vpart, colsumW, b_inp, cent, out, ss1);
  k8_finalnorm<<<8, 256, 0, stream>>>(ss1, out);
}

// Round 10
// 123.148 us; speedup vs baseline: 1.0400x; 1.0400x over previous
//
#include <hip/hip_runtime.h>
#include <hip/hip_bf16.h>
#include <math.h>

#define EPSN 1e-12f
typedef unsigned short ushort_t;

typedef float f32x4 __attribute__((ext_vector_type(4)));
typedef short s16x8 __attribute__((ext_vector_type(8)));
typedef unsigned short u16x8 __attribute__((ext_vector_type(8)));
typedef unsigned short u16x4 __attribute__((ext_vector_type(4)));

__device__ __forceinline__ void gload_lds16(const void* g, void* l) {
  __builtin_amdgcn_global_load_lds((const __attribute__((address_space(1))) void*)g,
                                   (__attribute__((address_space(3))) void*)l, 16, 0, 0);
}

// ---------------- K0: per-token sum of squares -> 8 partials ----------------
__global__ void k0_ssq(const float* __restrict__ x, float* __restrict__ ssq8) {
  int b8 = blockIdx.x >> 3;
  int cc = blockIdx.x & 7;
  int t = threadIdx.x;
  int s4 = (t & 15) * 4;
  int cg = t >> 4;
  const float* xp = x + (size_t)b8 * 65536 + (size_t)cc * 128 * 64;
  float4 a = {0.f, 0.f, 0.f, 0.f};
#pragma unroll
  for (int j = 0; j < 8; ++j) {
    int c = cg + j * 16;
    float4 v = *(const float4*)(xp + (size_t)c * 64 + s4);
    a.x = fmaf(v.x, v.x, a.x);
    a.y = fmaf(v.y, v.y, a.y);
    a.z = fmaf(v.z, v.z, a.z);
    a.w = fmaf(v.w, v.w, a.w);
  }
  __shared__ float red[16][68];
  *(float4*)&red[cg][s4] = a;
  __syncthreads();
  if (t < 64) {
    float s = 0.f;
#pragma unroll
    for (int g = 0; g < 16; ++g) s += red[g][t];
    ssq8[cc * 4096 + b8 * 64 + t] = s;
  }
}

// ---------------- K1: transpose + scale -> xnb bf16 [tm][c] ----------------
__global__ void k1_transpose(const float* __restrict__ x, const float* __restrict__ ssq8,
                             __hip_bfloat16* __restrict__ xnb) {
  int ct = blockIdx.x;
  int b8 = blockIdx.y;
  int t = threadIdx.x;
  __shared__ float tile[64][65];
  __shared__ float ivs[64];
  if (t < 64) {
    float s = 0.f;
#pragma unroll
    for (int cc = 0; cc < 8; ++cc) s += ssq8[cc * 4096 + b8 * 64 + t];
    ivs[t] = rsqrtf(fmaxf(s, 1e-24f));
  }
  int s = t & 63, cq = t >> 6;
  const float* xp = x + (size_t)b8 * 65536 + (size_t)ct * 64 * 64;
#pragma unroll
  for (int r = 0; r < 16; ++r) {
    int cl = cq * 16 + r;
    tile[cl][s] = xp[cl * 64 + s];
  }
  __syncthreads();
  int cl = t & 63, sq = t >> 6;
#pragma unroll
  for (int r = 0; r < 16; ++r) {
    int smm = sq * 16 + r;
    int tm = b8 * 64 + smm;
    xnb[(size_t)tm * 1024 + ct * 64 + cl] = __float2bfloat16(tile[cl][smm] * ivs[smm]);
  }
}

// ---------------- kpack2: stackedA rows 0-2047 (=Wib) + Wgkx (+gate, zero pad) + bWg + WibT ----
__global__ void kpack2(const float* __restrict__ Wi, const float* __restrict__ Wgk,
                       const float* __restrict__ W_g, const float* __restrict__ b_inp,
                       const float* __restrict__ b_g, __hip_bfloat16* __restrict__ oWi,
                       __hip_bfloat16* __restrict__ oWx, ushort_t* __restrict__ oWibT,
                       float* __restrict__ bWg) {
  int bid = blockIdx.x;
  int t = threadIdx.x;
  if (bid < 2048) {
    int i = (bid * 256 + t) * 4;
    float4 v = *(const float4*)(Wi + i);
    oWi[i + 0] = __float2bfloat16(v.x);
    oWi[i + 1] = __float2bfloat16(v.y);
    oWi[i + 2] = __float2bfloat16(v.z);
    oWi[i + 3] = __float2bfloat16(v.w);
  } else if (bid < 4096) {
    int i = ((bid - 2048) * 256 + t) * 4;
    float4 v = *(const float4*)(Wgk + i);
    oWx[i + 0] = __float2bfloat16(v.x);
    oWx[i + 1] = __float2bfloat16(v.y);
    oWx[i + 2] = __float2bfloat16(v.z);
    oWx[i + 3] = __float2bfloat16(v.w);
  } else if (bid < 4112) {
    int i = (bid - 4096) * 1024 + t * 4;  // 16 blocks: 8 gate rows
    float4 v = *(const float4*)(W_g + i);
    __hip_bfloat16* o = oWx + 1024 * 2048 + i;
    o[0] = __float2bfloat16(v.x);
    o[1] = __float2bfloat16(v.y);
    o[2] = __float2bfloat16(v.z);
    o[3] = __float2bfloat16(v.w);
  } else if (bid < 4352) {
    int i = (bid - 4112) * 1024 + t * 4;  // 240 blocks: 120 zero rows
    ushort_t* o = (ushort_t*)(oWx + 1032 * 2048) + i;
    *(u16x4*)o = (u16x4){0, 0, 0, 0};
  } else if (bid < 4360) {
    int j = bid - 4352;  // 0..7
    const float* row = W_g + (size_t)j * 2048;
    float s = 0.f;
    for (int c = t; c < 2048; c += 256) s = fmaf(b_inp[c], row[c], s);
    __shared__ float red[256];
    red[t] = s;
    __syncthreads();
    for (int o = 128; o > 0; o >>= 1) {
      if (t < o) red[t] += red[t + o];
      __syncthreads();
    }
    if (t == 0) bWg[j] = red[0] + b_g[j];
  } else {
    // WibT[1024 c][2048 c'] = cast-transpose of W_inp[2048 c'][1024 c]; 512 tiles 64x64
    int tt = bid - 4360;
    int cp0 = (tt >> 4) * 64;  // c' base
    int c0 = (tt & 15) * 64;   // c base
    __shared__ ushort_t tile[64][72];
    int r = t >> 2, cs = (t & 3) * 16;
    const float* src = Wi + (size_t)(cp0 + r) * 1024 + c0 + cs;
#pragma unroll
    for (int j = 0; j < 16; j += 4) {
      float4 v = *(const float4*)(src + j);
      __hip_bfloat16 h0 = __float2bfloat16(v.x), h1 = __float2bfloat16(v.y);
      __hip_bfloat16 h2 = __float2bfloat16(v.z), h3 = __float2bfloat16(v.w);
      tile[r][cs + j + 0] = *(ushort_t*)&h0;
      tile[r][cs + j + 1] = *(ushort_t*)&h1;
      tile[r][cs + j + 2] = *(ushort_t*)&h2;
      tile[r][cs + j + 3] = *(ushort_t*)&h3;
    }
    __syncthreads();
    int c = t >> 2, ms = (t & 3) * 16;
    u16x8 o0, o1;
#pragma unroll
    for (int j = 0; j < 8; ++j) o0[j] = tile[ms + j][c];
#pragma unroll
    for (int j = 0; j < 8; ++j) o1[j] = tile[ms + 8 + j][c];
    ushort_t* dst = oWibT + (size_t)(c0 + c) * 2048 + cp0 + ms;
    *(u16x8*)dst = o0;
    *(u16x8*)(dst + 8) = o1;
  }
}

// ---------------- GEMM0 split-K: Wc4[s][1152][1024] = Wgkx[:,s*512:(s+1)*512] @ WibT^T ------
// 128x128 tile, 8 waves, BK=64, dbuf, swizzle, counted vmcnt. Kstride=2048, Kloop=512.
__launch_bounds__(512, 4)
__global__ void gemm0_splitk(const ushort_t* __restrict__ A, const ushort_t* __restrict__ B,
                             float* __restrict__ Cf) {
  const int Kstride = 2048, N = 1024;
  __shared__ alignas(16) ushort_t SH[32768];
  const int tid = threadIdx.x;
  const int m0 = blockIdx.y * 128, n0 = blockIdx.x * 128;
  const int s = blockIdx.z;
  const int koff = s * 512;
  const int w = tid >> 6, l = tid & 63;
  const int wr = w >> 2, wc = w & 3;
  const int srow = w * 8 + (l >> 3);
  const int ksw = ((l & 7) ^ (l >> 3)) * 8;
  const ushort_t* Ag0 = A + (size_t)(m0 + srow) * Kstride + ksw + koff;
  const ushort_t* Ag1 = A + (size_t)(m0 + 64 + srow) * Kstride + ksw + koff;
  const ushort_t* Bg0 = B + (size_t)(n0 + srow) * Kstride + ksw + koff;
  const ushort_t* Bg1 = B + (size_t)(n0 + 64 + srow) * Kstride + ksw + koff;
  const int l0 = w * 512;
  const int l1 = 4096 + w * 512;

  f32x4 acc[4][2];
#pragma unroll
  for (int i = 0; i < 4; ++i)
#pragma unroll
    for (int j = 0; j < 2; ++j) acc[i][j] = (f32x4){0.f, 0.f, 0.f, 0.f};

  const int sw = l & 7, qq = l >> 4;

#define ASH(buf) (SH + (buf)*8192)
#define BSH(buf) (SH + 16384 + (buf)*8192)
#define STAGE(buf, k0)                               \
  {                                                  \
    gload_lds16(Ag0 + (k0), ASH(buf) + l0);          \
    gload_lds16(Ag1 + (k0), ASH(buf) + l1);          \
    gload_lds16(Bg0 + (k0), BSH(buf) + l0);          \
    gload_lds16(Bg1 + (k0), BSH(buf) + l1);          \
  }
#define COMPUTE(buf)                                                                     \
  {                                                                                      \
    s16x8 af[4][2], bf[2][2];                                                            \
    _Pragma("unroll") for (int kk = 0; kk < 2; ++kk) {                                   \
      int slot = (((kk << 2) + qq) ^ sw) * 8;                                            \
      _Pragma("unroll") for (int mi = 0; mi < 4; ++mi)                                   \
          af[mi][kk] = *(const s16x8*)&ASH(buf)[(wr * 64 + mi * 16 + (l & 15)) * 64 +    \
                                               slot];                                   \
      _Pragma("unroll") for (int ni = 0; ni < 2; ++ni)                                   \
          bf[ni][kk] = *(const s16x8*)&BSH(buf)[(wc * 32 + ni * 16 + (l & 15)) * 64 +    \
                                               slot];                                   \
    }                                                                                    \
    _Pragma("unroll") for (int kk = 0; kk < 2; ++kk)                                     \
        _Pragma("unroll") for (int mi = 0; mi < 4; ++mi)                                 \
            _Pragma("unroll") for (int ni = 0; ni < 2; ++ni)                             \
                acc[mi][ni] = __builtin_amdgcn_mfma_f32_16x16x32_bf16(af[mi][kk],        \
                                                                     bf[ni][kk],        \
                                                                     acc[mi][ni], 0, 0, 0); \
  }

  STAGE(0, 0);
  int buf = 0;
  for (int t = 0; t < 7; ++t) {  // 8 steps of BK=64 -> K=512
    STAGE(buf ^ 1, (t + 1) << 6);
    asm volatile("s_waitcnt vmcnt(4)" ::: "memory");
    __builtin_amdgcn_s_barrier();
    asm volatile("" ::: "memory");
    COMPUTE(buf);
    asm volatile("" ::: "memory");
    __builtin_amdgcn_s_barrier();
    buf ^= 1;
  }
  asm volatile("s_waitcnt vmcnt(0)" ::: "memory");
  __builtin_amdgcn_s_barrier();
  asm volatile("" ::: "memory");
  COMPUTE(buf);
#undef STAGE
#undef COMPUTE
#undef ASH
#undef BSH

  float* Co = Cf + (size_t)s * 1152 * 1024;
#pragma unroll
  for (int mi = 0; mi < 4; ++mi) {
    int row = m0 + wr * 64 + mi * 16 + (l >> 4) * 4;
#pragma unroll
    for (int ni = 0; ni < 2; ++ni) {
      int col = n0 + wc * 32 + ni * 16 + (l & 15);
#pragma unroll
      for (int r = 0; r < 4; ++r)
        Co[(size_t)(row + r) * N + col] = acc[mi][ni][r];
    }
  }
}

// ---------------- kpackC: sum 4 split-K partials -> bf16 into stackedA rows 2048+ ----------
__global__ void kpackC(const float* __restrict__ Wc4, ushort_t* __restrict__ dst) {
  int i = (blockIdx.x * 256 + threadIdx.x) * 4;
  float4 a = *(const float4*)(Wc4 + i);
  float4 b = *(const float4*)(Wc4 + 1179648 + i);
  float4 c = *(const float4*)(Wc4 + 2359296 + i);
  float4 d = *(const float4*)(Wc4 + 3538944 + i);
  float4 sv = {a.x + b.x + c.x + d.x, a.y + b.y + c.y + d.y,
               a.z + b.z + c.z + d.z, a.w + b.w + c.w + d.w};
  u16x4 o;
  __hip_bfloat16 h0 = __float2bfloat16(sv.x), h1 = __float2bfloat16(sv.y);
  __hip_bfloat16 h2 = __float2bfloat16(sv.z), h3 = __float2bfloat16(sv.w);
  o[0] = *(ushort_t*)&h0; o[1] = *(ushort_t*)&h1;
  o[2] = *(ushort_t*)&h2; o[3] = *(ushort_t*)&h3;
  *(u16x4*)(dst + i) = o;
}

// ---------------- big stacked GEMM: C[3200,4096] = stackedA[3200,1024] @ xnb[4096,1024]^T ----
__launch_bounds__(512, 4)
__global__ void gemm_nt_bf16(const ushort_t* __restrict__ A, const ushort_t* __restrict__ B,
                             ushort_t* __restrict__ C, int K, int N) {
  __shared__ alignas(16) ushort_t SH[32768];
  const int tid = threadIdx.x;
  const int m0 = blockIdx.y * 128, n0 = blockIdx.x * 128;
  const int w = tid >> 6, l = tid & 63;
  const int wr = w >> 2, wc = w & 3;
  const int srow = w * 8 + (l >> 3);
  const int ksw = ((l & 7) ^ (l >> 3)) * 8;
  const ushort_t* Ag0 = A + (size_t)(m0 + srow) * K + ksw;
  const ushort_t* Ag1 = A + (size_t)(m0 + 64 + srow) * K + ksw;
  const ushort_t* Bg0 = B + (size_t)(n0 + srow) * K + ksw;
  const ushort_t* Bg1 = B + (size_t)(n0 + 64 + srow) * K + ksw;
  const int l0 = w * 512;
  const int l1 = 4096 + w * 512;

  f32x4 acc[4][2];
#pragma unroll
  for (int i = 0; i < 4; ++i)
#pragma unroll
    for (int j = 0; j < 2; ++j) acc[i][j] = (f32x4){0.f, 0.f, 0.f, 0.f};

  const int sw = l & 7, qq = l >> 4;

#define ASH(buf) (SH + (buf)*8192)
#define BSH(buf) (SH + 16384 + (buf)*8192)
#define STAGE(buf, k0)                               \
  {                                                  \
    gload_lds16(Ag0 + (k0), ASH(buf) + l0);          \
    gload_lds16(Ag1 + (k0), ASH(buf) + l1);          \
    gload_lds16(Bg0 + (k0), BSH(buf) + l0);          \
    gload_lds16(Bg1 + (k0), BSH(buf) + l1);          \
  }
#define COMPUTE(buf)                                                                     \
  {                                                                                      \
    s16x8 af[4][2], bf[2][2];                                                            \
    _Pragma("unroll") for (int kk = 0; kk < 2; ++kk) {                                   \
      int slot = (((kk << 2) + qq) ^ sw) * 8;                                            \
      _Pragma("unroll") for (int mi = 0; mi < 4; ++mi)                                   \
          af[mi][kk] = *(const s16x8*)&ASH(buf)[(wr * 64 + mi * 16 + (l & 15)) * 64 +    \
                                               slot];                                   \
      _Pragma("unroll") for (int ni = 0; ni < 2; ++ni)                                   \
          bf[ni][kk] = *(const s16x8*)&BSH(buf)[(wc * 32 + ni * 16 + (l & 15)) * 64 +    \
                                               slot];                                   \
    }                                                                                    \
    _Pragma("unroll") for (int kk = 0; kk < 2; ++kk)                                     \
        _Pragma("unroll") for (int mi = 0; mi < 4; ++mi)                                 \
            _Pragma("unroll") for (int ni = 0; ni < 2; ++ni)                             \
                acc[mi][ni] = __builtin_amdgcn_mfma_f32_16x16x32_bf16(af[mi][kk],        \
                                                                     bf[ni][kk],        \
                                                                     acc[mi][ni], 0, 0, 0); \
  }

  const int nt = K >> 6;
  STAGE(0, 0);
  int buf = 0;
  for (int t = 0; t < nt - 1; ++t) {
    STAGE(buf ^ 1, (t + 1) << 6);
    asm volatile("s_waitcnt vmcnt(4)" ::: "memory");
    __builtin_amdgcn_s_barrier();
    asm volatile("" ::: "memory");
    COMPUTE(buf);
    asm volatile("" ::: "memory");
    __builtin_amdgcn_s_barrier();
    buf ^= 1;
  }
  asm volatile("s_waitcnt vmcnt(0)" ::: "memory");
  __builtin_amdgcn_s_barrier();
  asm volatile("" ::: "memory");
  COMPUTE(buf);
#undef STAGE
#undef COMPUTE
#undef ASH
#undef BSH

#pragma unroll
  for (int mi = 0; mi < 4; ++mi) {
    int row = m0 + wr * 64 + mi * 16 + (l >> 4) * 4;
#pragma unroll
    for (int ni = 0; ni < 2; ++ni) {
      int col = n0 + wc * 32 + ni * 16 + (l & 15);
#pragma unroll
      for (int r = 0; r < 4; ++r) {
        __hip_bfloat16 hb = __float2bfloat16(acc[mi][ni][r]);
        C[(size_t)(row + r) * N + col] = *(ushort_t*)&hb;
      }
    }
  }
}

// ---------------- K5: row softmax over tokens + gate sigmoid, one wave per (q,b) ----------------
// logitsTb bf16 [1152 q][4096 tm]: rows 0-1023 cluster logits, rows 1024-1031 gate logits.
__launch_bounds__(256)
__global__ void k5_softmax(const ushort_t* __restrict__ logitsTb, const float* __restrict__ bWg,
                           float* __restrict__ colsumW, ushort_t* __restrict__ wbT) {
  int wv = (blockIdx.x << 2) + (threadIdx.x >> 6);
  int q = wv >> 3, b = wv & 7;
  int l = threadIdx.x & 63;
  int g = q >> 7;
  size_t base = (size_t)q * 4096 + b * 512 + l * 8;
  u16x8 v8 = *(const u16x8*)(logitsTb + base);
  float vs[8];
#pragma unroll
  for (int i = 0; i < 8; ++i) vs[i] = __uint_as_float(((unsigned)v8[i]) << 16);
  float M = vs[0];
#pragma unroll
  for (int i = 1; i < 8; ++i) M = fmaxf(M, vs[i]);
#pragma unroll
  for (int m = 1; m < 64; m <<= 1) M = fmaxf(M, __shfl_xor(M, m, 64));
  float e[8], S = 0.f;
#pragma unroll
  for (int i = 0; i < 8; ++i) {
    e[i] = expf(vs[i] - M);
    S += e[i];
  }
#pragma unroll
  for (int m = 1; m < 64; m <<= 1) S += __shfl_xor(S, m, 64);
  float R = 1.0f / S;
  u16x8 g8 = *(const u16x8*)(logitsTb + (size_t)(1024 + g) * 4096 + b * 512 + l * 8);
  float bg = bWg[g];
  float wv8[8], wsum = 0.f;
#pragma unroll
  for (int i = 0; i < 8; ++i) {
    float gl = __uint_as_float(((unsigned)g8[i]) << 16);
    float ag = 1.0f / (1.0f + expf(-(gl + bg)));
    wv8[i] = e[i] * R * ag;
    wsum += wv8[i];
  }
#pragma unroll
  for (int m = 1; m < 64; m <<= 1) wsum += __shfl_xor(wsum, m, 64);
  if (l == 0) colsumW[b * 1024 + q] = wsum;
  u16x8 o;
#pragma unroll
  for (int i = 0; i < 8; ++i) {
    __hip_bfloat16 hb = __float2bfloat16(wv8[i]);
    o[i] = *(ushort_t*)&hb;
  }
  *(u16x8*)(wbT + base) = o;
}

// ---------------- K6: VLAD einsum via MFMA, 64x64 tile, m-split 8, counted vmcnt ----------------
__launch_bounds__(256)
__global__ void k6_vlad_mfma(const ushort_t* __restrict__ wbT, const ushort_t* __restrict__ YcT,
                             float* __restrict__ vpart) {
  int kt = blockIdx.x >> 2, dt = blockIdx.x & 3;
  int ms = blockIdx.y, b = blockIdx.z;  // ms 0..7 (64 m each)
  __shared__ alignas(16) ushort_t Ash[2][4096];
  __shared__ alignas(16) ushort_t Bsh[2][4096];
  const int tid = threadIdx.x;
  const int w = tid >> 6, l = tid & 63;
  const int wr = w >> 1, wc = w & 1;
  const int crow = l >> 3;
  const int ksw = ((l & 7) ^ crow) * 8;

  const ushort_t* Ap[2];
  const ushort_t* Bp[2];
  int loff[2];
#pragma unroll
  for (int c = 0; c < 2; ++c) {
    int chunk = w * 2 + c;  // 0..7
    Ap[c] = wbT + (size_t)(kt * 64 + chunk * 8 + crow) * 4096 + b * 512 + ms * 64 + ksw;
    Bp[c] = YcT + (size_t)(dt * 64 + chunk * 8 + crow) * 4096 + b * 512 + ms * 64 + ksw;
    loff[c] = chunk * 512;
  }

  f32x4 acc[2][2];
#pragma unroll
  for (int i = 0; i < 2; ++i)
#pragma unroll
    for (int j = 0; j < 2; ++j) acc[i][j] = (f32x4){0.f, 0.f, 0.f, 0.f};

  const int sw = l & 7, qq = l >> 4;

#define STAGE6(buf, g)                                                       \
  {                                                                          \
    size_t offA = (size_t)(g)*524288;                                        \
    size_t offB = (size_t)(g)*1048576;                                       \
    gload_lds16(Ap[0] + offA, &Ash[buf][loff[0]]);                           \
    gload_lds16(Ap[1] + offA, &Ash[buf][loff[1]]);                           \
    gload_lds16(Bp[0] + offB, &Bsh[buf][loff[0]]);                           \
    gload_lds16(Bp[1] + offB, &Bsh[buf][loff[1]]);                           \
  }
#define COMPUTE6(buf)                                                                    \
  {                                                                                      \
    s16x8 af[2][2], bf[2][2];                                                            \
    _Pragma("unroll") for (int kk = 0; kk < 2; ++kk) {                                   \
      int slot = (((kk << 2) + qq) ^ sw) * 8;                                            \
      _Pragma("unroll") for (int mi = 0; mi < 2; ++mi) {                                 \
        af[mi][kk] = *(const s16x8*)&Ash[buf][(wr * 32 + mi * 16 + (l & 15)) * 64 +      \
                                             slot];                                     \
        bf[mi][kk] = *(const s16x8*)&Bsh[buf][(wc * 32 + mi * 16 + (l & 15)) * 64 +      \
                                             slot];                                     \
      }                                                                                  \
    }                                                                                    \
    _Pragma("unroll") for (int kk = 0; kk < 2; ++kk)                                     \
        _Pragma("unroll") for (int mi = 0; mi < 2; ++mi)                                 \
            _Pragma("unroll") for (int ni = 0; ni < 2; ++ni)                             \
                acc[mi][ni] = __builtin_amdgcn_mfma_f32_16x16x32_bf16(af[mi][kk],        \
                                                                     bf[ni][kk],        \
                                                                     acc[mi][ni], 0, 0, 0); \
  }

  STAGE6(0, 0);
  int buf = 0;
  for (int s = 0; s < 7; ++s) {  // 8 steps: one per g
    STAGE6(buf ^ 1, s + 1);
    asm volatile("s_waitcnt vmcnt(4)" ::: "memory");
    __builtin_amdgcn_s_barrier();
    asm volatile("" ::: "memory");
    COMPUTE6(buf);
    asm volatile("" ::: "memory");
    __builtin_amdgcn_s_barrier();
    buf ^= 1;
  }
  asm volatile("s_waitcnt vmcnt(0)" ::: "memory");
  __builtin_amdgcn_s_barrier();
  asm volatile("" ::: "memory");
  COMPUTE6(buf);
#undef STAGE6
#undef COMPUTE6

#pragma unroll
  for (int mi = 0; mi < 2; ++mi) {
    int row = kt * 64 + wr * 32 + mi * 16 + (l >> 4) * 4;
#pragma unroll
    for (int ni = 0; ni < 2; ++ni) {
      int col = dt * 64 + wc * 32 + ni * 16 + (l & 15);
#pragma unroll
      for (int r = 0; r < 4; ++r)
        vpart[((size_t)(ms * 8 + b) * 128 + row + r) * 256 + col] = acc[mi][ni][r];
    }
  }
}

// ---------------- K7: combine 8 partials + bias-part - S*centroid, intra-normalize ----------------
__global__ void k7_intranorm(const float* __restrict__ vpart, const float* __restrict__ colsumW,
                             const float* __restrict__ b_inp, const float* __restrict__ cent,
                             float* __restrict__ out, float* __restrict__ ss1) {
  int k = blockIdx.x;
  int b = blockIdx.y;
  int d = threadIdx.x;
  float S = 0.f, bp = 0.f;
#pragma unroll
  for (int g = 0; g < 8; ++g) {
    float cw = colsumW[b * 1024 + g * 128 + k];
    S += cw;
    bp = fmaf(b_inp[g * 256 + d], cw, bp);
  }
  size_t off = ((size_t)b * 128 + k) * 256 + d;
  float v = bp - S * cent[(size_t)k * 256 + d];
#pragma unroll
  for (int i = 0; i < 8; ++i) v += vpart[off + (size_t)i * 262144];
  float ss = v * v;
#pragma unroll
  for (int m = 1; m < 64; m <<= 1) ss += __shfl_xor(ss, m, 64);
  __shared__ float red[4];
  int lane = d & 63, wv = d >> 6;
  if (lane == 0) red[wv] = ss;
  __syncthreads();
  float tot = red[0] + red[1] + red[2] + red[3];
  float rinv = 1.0f / fmaxf(sqrtf(tot), EPSN);
  out[off] = v * rinv;
  if (d == 0) ss1[b * 128 + k] = tot * rinv * rinv;
}

// ---------------- K8: final global L2 norm ----------------
__global__ void k8_finalnorm(const float* __restrict__ ss1, float* __restrict__ out) {
  int b = blockIdx.x;
  int t = threadIdx.x;
  __shared__ float red[256];
  red[t] = (t < 128) ? ss1[b * 128 + t] : 0.f;
  __syncthreads();
  for (int o = 128; o > 0; o >>= 1) {
    if (t < o) red[t] += red[t + o];
    __syncthreads();
  }
  float rinv = 1.0f / fmaxf(sqrtf(red[0]), EPSN);
  float* op = out + (size_t)b * 32768;
  for (int i = t; i < 32768; i += 256) op[i] *= rinv;
}

extern "C" void kernel_launch(void* const* d_in, const int* in_sizes, int n_in,
                              void* d_out, int out_size, void* d_ws, size_t ws_size,
                              hipStream_t stream) {
  const float* x     = (const float*)d_in[0];
  const float* W_inp = (const float*)d_in[1];
  const float* b_inp = (const float*)d_in[2];
  const float* W_g   = (const float*)d_in[3];
  const float* b_g   = (const float*)d_in[4];
  const float* W_gk  = (const float*)d_in[5];
  // b_gk (d_in[6]) cancels in the token-axis softmax — unused.
  const float* cent  = (const float*)d_in[7];
  float* out = (float*)d_out;
  float* ws = (float*)d_ws;

  // workspace layout (float offsets), total 12,559,424 floats = 50.2 MB
  float* ssq8    = ws + 0;         // 32768
  float* colsumW = ws + 32768;     // 8192
  float* ss1     = ws + 40960;     // 1024
  float* bWg     = ws + 41984;     // 64
  ushort_t* xnb  = (ushort_t*)(ws + 42048);     // [4096][1024] bf16 (2097152 fl)
  ushort_t* wbT  = xnb;                         // alias (xnb dead after bigGEMM)
  ushort_t* stackedA = (ushort_t*)(ws + 2139200);  // [3200][1024] bf16 (1638400 fl)
  ushort_t* WibT = (ushort_t*)(ws + 3777600);   // [1024][2048] bf16 (1048576 fl)
  ushort_t* Wgkx = (ushort_t*)(ws + 4826176);   // [1152][2048] bf16 (1179648 fl)
  float* vpart   = ws + 3777600;   // 2097152 fl, aliases WibT+Wgkx (dead after GEMM0)
  float* Wc4     = ws + 6005824;   // [4][1152][1024] f32 (4718592 fl), dead after kpackC
  ushort_t* Cstacked = (ushort_t*)(ws + 6005824);  // [3200][4096] bf16 (6553600 fl), over Wc4
  ushort_t* YcT      = Cstacked;                   // rows 0-2047
  ushort_t* logitsTb = Cstacked + (size_t)2048 * 4096;  // rows 2048-3199

  k0_ssq<<<512, 256, 0, stream>>>(x, ssq8);
  k1_transpose<<<dim3(16, 64), 256, 0, stream>>>(x, ssq8, (__hip_bfloat16*)xnb);
  kpack2<<<4872, 256, 0, stream>>>(W_inp, W_gk, W_g, b_inp, b_g,
                                   (__hip_bfloat16*)stackedA, (__hip_bfloat16*)Wgkx, WibT, bWg);
  // GEMM0 split-K x4: Wc4[s] = Wgkx[:, s*512..] @ WibT[:, s*512..]^T
  gemm0_splitk<<<dim3(8, 9, 4), 512, 0, stream>>>(Wgkx, WibT, Wc4);
  // pack: stackedA rows 2048-3199 = bf16(sum_s Wc4[s])
  kpackC<<<1152, 256, 0, stream>>>(Wc4, stackedA + (size_t)2048 * 1024);
  // big stacked GEMM: Cstacked[3200,4096] = stackedA @ xnb^T
  //   rows 0-2047 -> YcT ; rows 2048-3071 -> cluster logits ; 3072-3079 -> gate logits
  gemm_nt_bf16<<<dim3(32, 25), 512, 0, stream>>>(stackedA, xnb, Cstacked, 1024, 4096);
  k5_softmax<<<2048, 256, 0, stream>>>(logitsTb, bWg, colsumW, wbT);
  k6_vlad_mfma<<<dim3(8, 8, 8), 256, 0, stream>>>(wbT, YcT, vpart);
  k7_intranorm<<<dim3(128, 8), 256, 0, stream>>>(vpart, colsumW, b_inp, cent, out, ss1);
  k8_finalnorm<<<8, 256, 0, stream>>>(ss1, out);
}

// Round 11
// 119.417 us; speedup vs baseline: 1.0725x; 1.0312x over previous
//
#include <hip/hip_runtime.h>
#include <hip/hip_bf16.h>
#include <math.h>

#define EPSN 1e-12f
typedef unsigned short ushort_t;

typedef float f32x4 __attribute__((ext_vector_type(4)));
typedef short s16x8 __attribute__((ext_vector_type(8)));
typedef unsigned short u16x8 __attribute__((ext_vector_type(8)));
typedef unsigned short u16x4 __attribute__((ext_vector_type(4)));

__device__ __forceinline__ void gload_lds16(const void* g, void* l) {
  __builtin_amdgcn_global_load_lds((const __attribute__((address_space(1))) void*)g,
                                   (__attribute__((address_space(3))) void*)l, 16, 0, 0);
}

// ---------------- K0: per-token sum of squares -> 8 partials ----------------
__global__ void k0_ssq(const float* __restrict__ x, float* __restrict__ ssq8) {
  int b8 = blockIdx.x >> 3;
  int cc = blockIdx.x & 7;
  int t = threadIdx.x;
  int s4 = (t & 15) * 4;
  int cg = t >> 4;
  const float* xp = x + (size_t)b8 * 65536 + (size_t)cc * 128 * 64;
  float4 a = {0.f, 0.f, 0.f, 0.f};
#pragma unroll
  for (int j = 0; j < 8; ++j) {
    int c = cg + j * 16;
    float4 v = *(const float4*)(xp + (size_t)c * 64 + s4);
    a.x = fmaf(v.x, v.x, a.x);
    a.y = fmaf(v.y, v.y, a.y);
    a.z = fmaf(v.z, v.z, a.z);
    a.w = fmaf(v.w, v.w, a.w);
  }
  __shared__ float red[16][68];
  *(float4*)&red[cg][s4] = a;
  __syncthreads();
  if (t < 64) {
    float s = 0.f;
#pragma unroll
    for (int g = 0; g < 16; ++g) s += red[g][t];
    ssq8[cc * 4096 + b8 * 64 + t] = s;
  }
}

// ---------------- K1: transpose + scale -> xnb bf16 [tm][c] ----------------
__global__ void k1_transpose(const float* __restrict__ x, const float* __restrict__ ssq8,
                             __hip_bfloat16* __restrict__ xnb) {
  int ct = blockIdx.x;
  int b8 = blockIdx.y;
  int t = threadIdx.x;
  __shared__ float tile[64][65];
  __shared__ float ivs[64];
  if (t < 64) {
    float s = 0.f;
#pragma unroll
    for (int cc = 0; cc < 8; ++cc) s += ssq8[cc * 4096 + b8 * 64 + t];
    ivs[t] = rsqrtf(fmaxf(s, 1e-24f));
  }
  int s = t & 63, cq = t >> 6;
  const float* xp = x + (size_t)b8 * 65536 + (size_t)ct * 64 * 64;
#pragma unroll
  for (int r = 0; r < 16; ++r) {
    int cl = cq * 16 + r;
    tile[cl][s] = xp[cl * 64 + s];
  }
  __syncthreads();
  int cl = t & 63, sq = t >> 6;
#pragma unroll
  for (int r = 0; r < 16; ++r) {
    int smm = sq * 16 + r;
    int tm = b8 * 64 + smm;
    xnb[(size_t)tm * 1024 + ct * 64 + cl] = __float2bfloat16(tile[cl][smm] * ivs[smm]);
  }
}

// ---------------- kpack2: stackedA rows 0-2047 (=Wib) + pad rows 3200-3327 + Wgkx
//                  (+gate, zero pad) + bWg + WibT ----------------
__global__ void kpack2(const float* __restrict__ Wi, const float* __restrict__ Wgk,
                       const float* __restrict__ W_g, const float* __restrict__ b_inp,
                       const float* __restrict__ b_g, __hip_bfloat16* __restrict__ oWi,
                       __hip_bfloat16* __restrict__ oWx, ushort_t* __restrict__ oWibT,
                       float* __restrict__ bWg) {
  int bid = blockIdx.x;
  int t = threadIdx.x;
  if (bid < 2048) {
    int i = (bid * 256 + t) * 4;
    float4 v = *(const float4*)(Wi + i);
    oWi[i + 0] = __float2bfloat16(v.x);
    oWi[i + 1] = __float2bfloat16(v.y);
    oWi[i + 2] = __float2bfloat16(v.z);
    oWi[i + 3] = __float2bfloat16(v.w);
  } else if (bid < 4096) {
    int i = ((bid - 2048) * 256 + t) * 4;
    float4 v = *(const float4*)(Wgk + i);
    oWx[i + 0] = __float2bfloat16(v.x);
    oWx[i + 1] = __float2bfloat16(v.y);
    oWx[i + 2] = __float2bfloat16(v.z);
    oWx[i + 3] = __float2bfloat16(v.w);
  } else if (bid < 4112) {
    int i = (bid - 4096) * 1024 + t * 4;  // 16 blocks: 8 gate rows
    float4 v = *(const float4*)(W_g + i);
    __hip_bfloat16* o = oWx + 1024 * 2048 + i;
    o[0] = __float2bfloat16(v.x);
    o[1] = __float2bfloat16(v.y);
    o[2] = __float2bfloat16(v.z);
    o[3] = __float2bfloat16(v.w);
  } else if (bid < 4352) {
    int i = (bid - 4112) * 1024 + t * 4;  // 240 blocks: 120 zero rows of Wgkx
    ushort_t* o = (ushort_t*)(oWx + 1032 * 2048) + i;
    *(u16x4*)o = (u16x4){0, 0, 0, 0};
  } else if (bid < 4360) {
    int j = bid - 4352;  // 0..7
    const float* row = W_g + (size_t)j * 2048;
    float s = 0.f;
    for (int c = t; c < 2048; c += 256) s = fmaf(b_inp[c], row[c], s);
    __shared__ float red[256];
    red[t] = s;
    __syncthreads();
    for (int o = 128; o > 0; o >>= 1) {
      if (t < o) red[t] += red[t + o];
      __syncthreads();
    }
    if (t == 0) bWg[j] = red[0] + b_g[j];
  } else if (bid < 4872) {
    // WibT[1024 c][2048 c'] = cast-transpose of W_inp[2048 c'][1024 c]; 512 tiles 64x64
    int tt = bid - 4360;
    int cp0 = (tt >> 4) * 64;  // c' base
    int c0 = (tt & 15) * 64;   // c base
    __shared__ ushort_t tile[64][72];
    int r = t >> 2, cs = (t & 3) * 16;
    const float* src = Wi + (size_t)(cp0 + r) * 1024 + c0 + cs;
#pragma unroll
    for (int j = 0; j < 16; j += 4) {
      float4 v = *(const float4*)(src + j);
      __hip_bfloat16 h0 = __float2bfloat16(v.x), h1 = __float2bfloat16(v.y);
      __hip_bfloat16 h2 = __float2bfloat16(v.z), h3 = __float2bfloat16(v.w);
      tile[r][cs + j + 0] = *(ushort_t*)&h0;
      tile[r][cs + j + 1] = *(ushort_t*)&h1;
      tile[r][cs + j + 2] = *(ushort_t*)&h2;
      tile[r][cs + j + 3] = *(ushort_t*)&h3;
    }
    __syncthreads();
    int c = t >> 2, ms = (t & 3) * 16;
    u16x8 o0, o1;
#pragma unroll
    for (int j = 0; j < 8; ++j) o0[j] = tile[ms + j][c];
#pragma unroll
    for (int j = 0; j < 8; ++j) o1[j] = tile[ms + 8 + j][c];
    ushort_t* dst = oWibT + (size_t)(c0 + c) * 2048 + cp0 + ms;
    *(u16x8*)dst = o0;
    *(u16x8*)(dst + 8) = o1;
  } else {
    // zero pad rows 3200-3327 of stackedA (128 rows): 128 blocks x 1024 elems
    int i = (bid - 4872) * 1024 + t * 4;
    ushort_t* o = (ushort_t*)oWi + (size_t)3200 * 1024 + i;
    *(u16x4*)o = (u16x4){0, 0, 0, 0};
  }
}

// ---------------- GEMM0 split-K: Wc4[s][1152][1024] = Wgkx[:,s*512:(s+1)*512] @ WibT^T ------
__launch_bounds__(512, 4)
__global__ void gemm0_splitk(const ushort_t* __restrict__ A, const ushort_t* __restrict__ B,
                             float* __restrict__ Cf) {
  const int Kstride = 2048, N = 1024;
  __shared__ alignas(16) ushort_t SH[32768];
  const int tid = threadIdx.x;
  const int m0 = blockIdx.y * 128, n0 = blockIdx.x * 128;
  const int s = blockIdx.z;
  const int koff = s * 512;
  const int w = tid >> 6, l = tid & 63;
  const int wr = w >> 2, wc = w & 3;
  const int srow = w * 8 + (l >> 3);
  const int ksw = ((l & 7) ^ (l >> 3)) * 8;
  const ushort_t* Ag0 = A + (size_t)(m0 + srow) * Kstride + ksw + koff;
  const ushort_t* Ag1 = A + (size_t)(m0 + 64 + srow) * Kstride + ksw + koff;
  const ushort_t* Bg0 = B + (size_t)(n0 + srow) * Kstride + ksw + koff;
  const ushort_t* Bg1 = B + (size_t)(n0 + 64 + srow) * Kstride + ksw + koff;
  const int l0 = w * 512;
  const int l1 = 4096 + w * 512;

  f32x4 acc[4][2];
#pragma unroll
  for (int i = 0; i < 4; ++i)
#pragma unroll
    for (int j = 0; j < 2; ++j) acc[i][j] = (f32x4){0.f, 0.f, 0.f, 0.f};

  const int sw = l & 7, qq = l >> 4;

#define ASH(buf) (SH + (buf)*8192)
#define BSH(buf) (SH + 16384 + (buf)*8192)
#define STAGE(buf, k0)                               \
  {                                                  \
    gload_lds16(Ag0 + (k0), ASH(buf) + l0);          \
    gload_lds16(Ag1 + (k0), ASH(buf) + l1);          \
    gload_lds16(Bg0 + (k0), BSH(buf) + l0);          \
    gload_lds16(Bg1 + (k0), BSH(buf) + l1);          \
  }
#define COMPUTE(buf)                                                                     \
  {                                                                                      \
    s16x8 af[4][2], bf[2][2];                                                            \
    _Pragma("unroll") for (int kk = 0; kk < 2; ++kk) {                                   \
      int slot = (((kk << 2) + qq) ^ sw) * 8;                                            \
      _Pragma("unroll") for (int mi = 0; mi < 4; ++mi)                                   \
          af[mi][kk] = *(const s16x8*)&ASH(buf)[(wr * 64 + mi * 16 + (l & 15)) * 64 +    \
                                               slot];                                   \
      _Pragma("unroll") for (int ni = 0; ni < 2; ++ni)                                   \
          bf[ni][kk] = *(const s16x8*)&BSH(buf)[(wc * 32 + ni * 16 + (l & 15)) * 64 +    \
                                               slot];                                   \
    }                                                                                    \
    _Pragma("unroll") for (int kk = 0; kk < 2; ++kk)                                     \
        _Pragma("unroll") for (int mi = 0; mi < 4; ++mi)                                 \
            _Pragma("unroll") for (int ni = 0; ni < 2; ++ni)                             \
                acc[mi][ni] = __builtin_amdgcn_mfma_f32_16x16x32_bf16(af[mi][kk],        \
                                                                     bf[ni][kk],        \
                                                                     acc[mi][ni], 0, 0, 0); \
  }

  STAGE(0, 0);
  int buf = 0;
  for (int t = 0; t < 7; ++t) {
    STAGE(buf ^ 1, (t + 1) << 6);
    asm volatile("s_waitcnt vmcnt(4)" ::: "memory");
    __builtin_amdgcn_s_barrier();
    asm volatile("" ::: "memory");
    COMPUTE(buf);
    asm volatile("" ::: "memory");
    __builtin_amdgcn_s_barrier();
    buf ^= 1;
  }
  asm volatile("s_waitcnt vmcnt(0)" ::: "memory");
  __builtin_amdgcn_s_barrier();
  asm volatile("" ::: "memory");
  COMPUTE(buf);
#undef STAGE
#undef COMPUTE
#undef ASH
#undef BSH

  float* Co = Cf + (size_t)s * 1152 * 1024;
#pragma unroll
  for (int mi = 0; mi < 4; ++mi) {
    int row = m0 + wr * 64 + mi * 16 + (l >> 4) * 4;
#pragma unroll
    for (int ni = 0; ni < 2; ++ni) {
      int col = n0 + wc * 32 + ni * 16 + (l & 15);
#pragma unroll
      for (int r = 0; r < 4; ++r)
        Co[(size_t)(row + r) * N + col] = acc[mi][ni][r];
    }
  }
}

// ---------------- kpackC: sum 4 split-K partials -> bf16 into stackedA rows 2048+ ----------
__global__ void kpackC(const float* __restrict__ Wc4, ushort_t* __restrict__ dst) {
  int i = (blockIdx.x * 256 + threadIdx.x) * 4;
  float4 a = *(const float4*)(Wc4 + i);
  float4 b = *(const float4*)(Wc4 + 1179648 + i);
  float4 c = *(const float4*)(Wc4 + 2359296 + i);
  float4 d = *(const float4*)(Wc4 + 3538944 + i);
  float4 sv = {a.x + b.x + c.x + d.x, a.y + b.y + c.y + d.y,
               a.z + b.z + c.z + d.z, a.w + b.w + c.w + d.w};
  u16x4 o;
  __hip_bfloat16 h0 = __float2bfloat16(sv.x), h1 = __float2bfloat16(sv.y);
  __hip_bfloat16 h2 = __float2bfloat16(sv.z), h3 = __float2bfloat16(sv.w);
  o[0] = *(ushort_t*)&h0; o[1] = *(ushort_t*)&h1;
  o[2] = *(ushort_t*)&h2; o[3] = *(ushort_t*)&h3;
  *(u16x4*)(dst + i) = o;
}

// ---------------- big stacked GEMM, 256x256 tile, BK=64, 8 waves, dbuf, swizzle ----------
// C[3328,4096] = stackedA[3328,1024] @ xnb[4096,1024]^T. Per-wave output 128x64.
// LDS 128 KB: A[2][256][64] | B[2][256][64], 16B-slot XOR-swizzle by row&7.
__launch_bounds__(512, 2)
__global__ void gemm256(const ushort_t* __restrict__ A, const ushort_t* __restrict__ B,
                        ushort_t* __restrict__ C, int K, int N) {
  __shared__ alignas(16) ushort_t SH[65536];  // 128 KB
  const int tid = threadIdx.x;
  const int m0 = blockIdx.y * 256, n0 = blockIdx.x * 256;
  const int w = tid >> 6, l = tid & 63;
  const int wr = w >> 2, wc = w & 3;  // 2 x 4 wave grid; per-wave 128m x 64n
  const int srow = w * 8 + (l >> 3);  // 0..63
  const int ksw = ((l & 7) ^ (l >> 3)) * 8;
  const ushort_t* Ag[4];
  const ushort_t* Bg[4];
#pragma unroll
  for (int p = 0; p < 4; ++p) {
    Ag[p] = A + (size_t)(m0 + p * 64 + srow) * K + ksw;
    Bg[p] = B + (size_t)(n0 + p * 64 + srow) * K + ksw;
  }
  const int ldst = w * 512;  // per-wave lane-linear dest base (elems)

  f32x4 acc[8][4];
#pragma unroll
  for (int i = 0; i < 8; ++i)
#pragma unroll
    for (int j = 0; j < 4; ++j) acc[i][j] = (f32x4){0.f, 0.f, 0.f, 0.f};

  const int sw = l & 7, qq = l >> 4;

#define ABASE(buf) (SH + (buf)*16384)
#define BBASE(buf) (SH + 32768 + (buf)*16384)
#define STAGE(buf, k0)                                           \
  {                                                              \
    _Pragma("unroll") for (int p = 0; p < 4; ++p)                \
        gload_lds16(Ag[p] + (k0), ABASE(buf) + p * 4096 + ldst); \
    _Pragma("unroll") for (int p = 0; p < 4; ++p)                \
        gload_lds16(Bg[p] + (k0), BBASE(buf) + p * 4096 + ldst); \
  }

#define COMPUTE(buf)                                                                      \
  {                                                                                       \
    const ushort_t* As = ABASE(buf);                                                      \
    const ushort_t* Bs = BBASE(buf);                                                      \
    _Pragma("unroll") for (int kk = 0; kk < 2; ++kk) {                                    \
      int slot = (((kk << 2) + qq) ^ sw) * 8;                                             \
      s16x8 bfr[4];                                                                       \
      _Pragma("unroll") for (int ni = 0; ni < 4; ++ni)                                    \
          bfr[ni] = *(const s16x8*)&Bs[(wc * 64 + ni * 16 + (l & 15)) * 64 + slot];       \
      _Pragma("unroll") for (int mi = 0; mi < 8; ++mi) {                                  \
        s16x8 a = *(const s16x8*)&As[(wr * 128 + mi * 16 + (l & 15)) * 64 + slot];        \
        _Pragma("unroll") for (int ni = 0; ni < 4; ++ni)                                  \
            acc[mi][ni] = __builtin_amdgcn_mfma_f32_16x16x32_bf16(a, bfr[ni],             \
                                                                 acc[mi][ni], 0, 0, 0);  \
      }                                                                                   \
    }                                                                                     \
  }

  const int nt = K >> 6;
  STAGE(0, 0);
  int buf = 0;
  for (int t = 0; t < nt - 1; ++t) {
    STAGE(buf ^ 1, (t + 1) << 6);
    asm volatile("s_waitcnt vmcnt(8)" ::: "memory");  // prev buf's 8 landed; 8 new in flight
    __builtin_amdgcn_s_barrier();
    asm volatile("" ::: "memory");
    COMPUTE(buf);
    asm volatile("" ::: "memory");
    __builtin_amdgcn_s_barrier();
    buf ^= 1;
  }
  asm volatile("s_waitcnt vmcnt(0)" ::: "memory");
  __builtin_amdgcn_s_barrier();
  asm volatile("" ::: "memory");
  COMPUTE(buf);
#undef STAGE
#undef COMPUTE
#undef ABASE
#undef BBASE

#pragma unroll
  for (int mi = 0; mi < 8; ++mi) {
    int row = m0 + wr * 128 + mi * 16 + (l >> 4) * 4;
#pragma unroll
    for (int ni = 0; ni < 4; ++ni) {
      int col = n0 + wc * 64 + ni * 16 + (l & 15);
#pragma unroll
      for (int r = 0; r < 4; ++r) {
        __hip_bfloat16 hb = __float2bfloat16(acc[mi][ni][r]);
        C[(size_t)(row + r) * N + col] = *(ushort_t*)&hb;
      }
    }
  }
}

// ---------------- K5: row softmax over tokens + gate sigmoid, one wave per (q,b) ----------------
__launch_bounds__(256)
__global__ void k5_softmax(const ushort_t* __restrict__ logitsTb, const float* __restrict__ bWg,
                           float* __restrict__ colsumW, ushort_t* __restrict__ wbT) {
  int wv = (blockIdx.x << 2) + (threadIdx.x >> 6);
  int q = wv >> 3, b = wv & 7;
  int l = threadIdx.x & 63;
  int g = q >> 7;
  size_t base = (size_t)q * 4096 + b * 512 + l * 8;
  u16x8 v8 = *(const u16x8*)(logitsTb + base);
  float vs[8];
#pragma unroll
  for (int i = 0; i < 8; ++i) vs[i] = __uint_as_float(((unsigned)v8[i]) << 16);
  float M = vs[0];
#pragma unroll
  for (int i = 1; i < 8; ++i) M = fmaxf(M, vs[i]);
#pragma unroll
  for (int m = 1; m < 64; m <<= 1) M = fmaxf(M, __shfl_xor(M, m, 64));
  float e[8], S = 0.f;
#pragma unroll
  for (int i = 0; i < 8; ++i) {
    e[i] = expf(vs[i] - M);
    S += e[i];
  }
#pragma unroll
  for (int m = 1; m < 64; m <<= 1) S += __shfl_xor(S, m, 64);
  float R = 1.0f / S;
  u16x8 g8 = *(const u16x8*)(logitsTb + (size_t)(1024 + g) * 4096 + b * 512 + l * 8);
  float bg = bWg[g];
  float wv8[8], wsum = 0.f;
#pragma unroll
  for (int i = 0; i < 8; ++i) {
    float gl = __uint_as_float(((unsigned)g8[i]) << 16);
    float ag = 1.0f / (1.0f + expf(-(gl + bg)));
    wv8[i] = e[i] * R * ag;
    wsum += wv8[i];
  }
#pragma unroll
  for (int m = 1; m < 64; m <<= 1) wsum += __shfl_xor(wsum, m, 64);
  if (l == 0) colsumW[b * 1024 + q] = wsum;
  u16x8 o;
#pragma unroll
  for (int i = 0; i < 8; ++i) {
    __hip_bfloat16 hb = __float2bfloat16(wv8[i]);
    o[i] = *(ushort_t*)&hb;
  }
  *(u16x8*)(wbT + base) = o;
}

// ---------------- K6: VLAD einsum via MFMA, 64x64 tile, m-split 8, counted vmcnt ----------------
__launch_bounds__(256)
__global__ void k6_vlad_mfma(const ushort_t* __restrict__ wbT, const ushort_t* __restrict__ YcT,
                             float* __restrict__ vpart) {
  int kt = blockIdx.x >> 2, dt = blockIdx.x & 3;
  int ms = blockIdx.y, b = blockIdx.z;
  __shared__ alignas(16) ushort_t Ash[2][4096];
  __shared__ alignas(16) ushort_t Bsh[2][4096];
  const int tid = threadIdx.x;
  const int w = tid >> 6, l = tid & 63;
  const int wr = w >> 1, wc = w & 1;
  const int crow = l >> 3;
  const int ksw = ((l & 7) ^ crow) * 8;

  const ushort_t* Ap[2];
  const ushort_t* Bp[2];
  int loff[2];
#pragma unroll
  for (int c = 0; c < 2; ++c) {
    int chunk = w * 2 + c;
    Ap[c] = wbT + (size_t)(kt * 64 + chunk * 8 + crow) * 4096 + b * 512 + ms * 64 + ksw;
    Bp[c] = YcT + (size_t)(dt * 64 + chunk * 8 + crow) * 4096 + b * 512 + ms * 64 + ksw;
    loff[c] = chunk * 512;
  }

  f32x4 acc[2][2];
#pragma unroll
  for (int i = 0; i < 2; ++i)
#pragma unroll
    for (int j = 0; j < 2; ++j) acc[i][j] = (f32x4){0.f, 0.f, 0.f, 0.f};

  const int sw = l & 7, qq = l >> 4;

#define STAGE6(buf, g)                                                       \
  {                                                                          \
    size_t offA = (size_t)(g)*524288;                                        \
    size_t offB = (size_t)(g)*1048576;                                       \
    gload_lds16(Ap[0] + offA, &Ash[buf][loff[0]]);                           \
    gload_lds16(Ap[1] + offA, &Ash[buf][loff[1]]);                           \
    gload_lds16(Bp[0] + offB, &Bsh[buf][loff[0]]);                           \
    gload_lds16(Bp[1] + offB, &Bsh[buf][loff[1]]);                           \
  }
#define COMPUTE6(buf)                                                                    \
  {                                                                                      \
    s16x8 af[2][2], bf[2][2];                                                            \
    _Pragma("unroll") for (int kk = 0; kk < 2; ++kk) {                                   \
      int slot = (((kk << 2) + qq) ^ sw) * 8;                                            \
      _Pragma("unroll") for (int mi = 0; mi < 2; ++mi) {                                 \
        af[mi][kk] = *(const s16x8*)&Ash[buf][(wr * 32 + mi * 16 + (l & 15)) * 64 +      \
                                             slot];                                     \
        bf[mi][kk] = *(const s16x8*)&Bsh[buf][(wc * 32 + mi * 16 + (l & 15)) * 64 +      \
                                             slot];                                     \
      }                                                                                  \
    }                                                                                    \
    _Pragma("unroll") for (int kk = 0; kk < 2; ++kk)                                     \
        _Pragma("unroll") for (int mi = 0; mi < 2; ++mi)                                 \
            _Pragma("unroll") for (int ni = 0; ni < 2; ++ni)                             \
                acc[mi][ni] = __builtin_amdgcn_mfma_f32_16x16x32_bf16(af[mi][kk],        \
                                                                     bf[ni][kk],        \
                                                                     acc[mi][ni], 0, 0, 0); \
  }

  STAGE6(0, 0);
  int buf = 0;
  for (int s = 0; s < 7; ++s) {
    STAGE6(buf ^ 1, s + 1);
    asm volatile("s_waitcnt vmcnt(4)" ::: "memory");
    __builtin_amdgcn_s_barrier();
    asm volatile("" ::: "memory");
    COMPUTE6(buf);
    asm volatile("" ::: "memory");
    __builtin_amdgcn_s_barrier();
    buf ^= 1;
  }
  asm volatile("s_waitcnt vmcnt(0)" ::: "memory");
  __builtin_amdgcn_s_barrier();
  asm volatile("" ::: "memory");
  COMPUTE6(buf);
#undef STAGE6
#undef COMPUTE6

#pragma unroll
  for (int mi = 0; mi < 2; ++mi) {
    int row = kt * 64 + wr * 32 + mi * 16 + (l >> 4) * 4;
#pragma unroll
    for (int ni = 0; ni < 2; ++ni) {
      int col = dt * 64 + wc * 32 + ni * 16 + (l & 15);
#pragma unroll
      for (int r = 0; r < 4; ++r)
        vpart[((size_t)(ms * 8 + b) * 128 + row + r) * 256 + col] = acc[mi][ni][r];
    }
  }
}

// ---------------- K7: combine 8 partials + bias-part - S*centroid, intra-normalize ----------------
__global__ void k7_intranorm(const float* __restrict__ vpart, const float* __restrict__ colsumW,
                             const float* __restrict__ b_inp, const float* __restrict__ cent,
                             float* __restrict__ out, float* __restrict__ ss1) {
  int k = blockIdx.x;
  int b = blockIdx.y;
  int d = threadIdx.x;
  float S = 0.f, bp = 0.f;
#pragma unroll
  for (int g = 0; g < 8; ++g) {
    float cw = colsumW[b * 1024 + g * 128 + k];
    S += cw;
    bp = fmaf(b_inp[g * 256 + d], cw, bp);
  }
  size_t off = ((size_t)b * 128 + k) * 256 + d;
  float v = bp - S * cent[(size_t)k * 256 + d];
#pragma unroll
  for (int i = 0; i < 8; ++i) v += vpart[off + (size_t)i * 262144];
  float ss = v * v;
#pragma unroll
  for (int m = 1; m < 64; m <<= 1) ss += __shfl_xor(ss, m, 64);
  __shared__ float red[4];
  int lane = d & 63, wv = d >> 6;
  if (lane == 0) red[wv] = ss;
  __syncthreads();
  float tot = red[0] + red[1] + red[2] + red[3];
  float rinv = 1.0f / fmaxf(sqrtf(tot), EPSN);
  out[off] = v * rinv;
  if (d == 0) ss1[b * 128 + k] = tot * rinv * rinv;
}

// ---------------- K8: final global L2 norm ----------------
__global__ void k8_finalnorm(const float* __restrict__ ss1, float* __restrict__ out) {
  int b = blockIdx.x;
  int t = threadIdx.x;
  __shared__ float red[256];
  red[t] = (t < 128) ? ss1[b * 128 + t] : 0.f;
  __syncthreads();
  for (int o = 128; o > 0; o >>= 1) {
    if (t < o) red[t] += red[t + o];
    __syncthreads();
  }
  float rinv = 1.0f / fmaxf(sqrtf(red[0]), EPSN);
  float* op = out + (size_t)b * 32768;
  for (int i = t; i < 32768; i += 256) op[i] *= rinv;
}

extern "C" void kernel_launch(void* const* d_in, const int* in_sizes, int n_in,
                              void* d_out, int out_size, void* d_ws, size_t ws_size,
                              hipStream_t stream) {
  const float* x     = (const float*)d_in[0];
  const float* W_inp = (const float*)d_in[1];
  const float* b_inp = (const float*)d_in[2];
  const float* W_g   = (const float*)d_in[3];
  const float* b_g   = (const float*)d_in[4];
  const float* W_gk  = (const float*)d_in[5];
  // b_gk (d_in[6]) cancels in the token-axis softmax — unused.
  const float* cent  = (const float*)d_in[7];
  float* out = (float*)d_out;
  float* ws = (float*)d_ws;

  // workspace layout (float offsets), total 12,887,104 floats = 51.5 MB
  float* ssq8    = ws + 0;         // 32768
  float* colsumW = ws + 32768;     // 8192
  float* ss1     = ws + 40960;     // 1024
  float* bWg     = ws + 41984;     // 64
  ushort_t* xnb  = (ushort_t*)(ws + 42048);        // [4096][1024] bf16 (2097152 fl)
  ushort_t* wbT  = xnb;                            // alias (xnb dead after gemm256)
  ushort_t* stackedA = (ushort_t*)(ws + 2139200);  // [3328][1024] bf16 (1703936 fl)
  ushort_t* WibT = (ushort_t*)(ws + 3843136);      // [1024][2048] bf16 (1048576 fl)
  ushort_t* Wgkx = (ushort_t*)(ws + 4891712);      // [1152][2048] bf16 (1179648 fl)
  float* vpart   = ws + 3843136;   // 2097152 fl, aliases WibT+Wgkx (dead after GEMM0)
  float* Wc4     = ws + 6071360;   // [4][1152][1024] f32 (4718592 fl), dead after kpackC
  ushort_t* Cstacked = (ushort_t*)(ws + 6071360);  // [3328][4096] bf16 (6815744 fl), over Wc4
  ushort_t* YcT      = Cstacked;                   // rows 0-2047
  ushort_t* logitsTb = Cstacked + (size_t)2048 * 4096;  // rows 2048-3199

  k0_ssq<<<512, 256, 0, stream>>>(x, ssq8);
  k1_transpose<<<dim3(16, 64), 256, 0, stream>>>(x, ssq8, (__hip_bfloat16*)xnb);
  kpack2<<<5000, 256, 0, stream>>>(W_inp, W_gk, W_g, b_inp, b_g,
                                   (__hip_bfloat16*)stackedA, (__hip_bfloat16*)Wgkx, WibT, bWg);
  // GEMM0 split-K x4: Wc4[s] = Wgkx[:, s*512..] @ WibT[:, s*512..]^T
  gemm0_splitk<<<dim3(8, 9, 4), 512, 0, stream>>>(Wgkx, WibT, Wc4);
  // pack: stackedA rows 2048-3199 = bf16(sum_s Wc4[s])
  kpackC<<<1152, 256, 0, stream>>>(Wc4, stackedA + (size_t)2048 * 1024);
  // big stacked GEMM (256^2 tiles): Cstacked[3328,4096] = stackedA @ xnb^T
  gemm256<<<dim3(16, 13), 512, 0, stream>>>(stackedA, xnb, Cstacked, 1024, 4096);
  k5_softmax<<<2048, 256, 0, stream>>>(logitsTb, bWg, colsumW, wbT);
  k6_vlad_mfma<<<dim3(8, 8, 8), 256, 0, stream>>>(wbT, YcT, vpart);
  k7_intranorm<<<dim3(128, 8), 256, 0, stream>>>(vpart, colsumW, b_inp, cent, out, ss1);
  k8_finalnorm<<<8, 256, 0, stream>>>(ss1, out);
}